// Round 9
// baseline (316.401 us; speedup 1.0000x reference)
//
#include <hip/hip_runtime.h>
#include <math.h>

typedef __attribute__((ext_vector_type(8))) short bf16x8;
typedef __attribute__((ext_vector_type(4))) float f32x4;
#define MFMA16(a, b, c) __builtin_amdgcn_mfma_f32_16x16x32_bf16(a, b, c, 0, 0, 0)

__device__ __forceinline__ unsigned short f2bf(float f) {
  unsigned u = __float_as_uint(f);
  return (unsigned short)((u + 0x7fffu + ((u >> 16) & 1u)) >> 16);  // RNE
}
__device__ __forceinline__ float b2f(unsigned short u) {
  return __uint_as_float((unsigned)u << 16);
}
__device__ __forceinline__ bf16x8 ldb16x8(const unsigned short* p) {
  union { uint4 u; bf16x8 s; } cv;
  cv.u = *(const uint4*)p;
  return cv.s;
}

// ---------------------------------------------------------------------------
// prep_k: fused pack(rel,mask) + cvt(x,W*) + wemb fold. One launch.
// blocks [0,3584): cvt | [3584,4608): pack | [4608,4800): wemb (24 units x 8 cc)
// Wq pre-scaled by 0.125 so QK^T exits attention MFMA already /8.
// ---------------------------------------------------------------------------
__global__ __launch_bounds__(256) void prep_k(
    const float* __restrict__ x, const int* __restrict__ rel,
    const unsigned char* __restrict__ mask, const float* __restrict__ qpe,
    const float* __restrict__ kpe, const float* __restrict__ Wq,
    const float* __restrict__ Wk, const float* __restrict__ Wv,
    const float* __restrict__ Wo, unsigned short* __restrict__ x16,
    unsigned short* __restrict__ w16q, unsigned short* __restrict__ w16k,
    unsigned short* __restrict__ w16v, unsigned short* __restrict__ w16o,
    unsigned short* __restrict__ wqp, unsigned short* __restrict__ wkp,
    unsigned char* __restrict__ pk8) {
  const int bid = blockIdx.x, t = threadIdx.x;
  if (bid < 3584) {  // ---- cvt: fp32 -> bf16 (x, Wq*0.125, Wk, Wv, Wo) ----
    int i = bid * 256 + t;
    const float* src; unsigned short* dst; int off; float sc = 1.f;
    if (i < 524288)      { src = x;  dst = x16;  off = i; }
    else if (i < 589824) { src = Wq; dst = w16q; off = i - 524288; sc = 0.125f; }
    else if (i < 720896) { src = Wk; dst = w16k; off = i - 589824; }
    else if (i < 851968) { src = Wv; dst = w16v; off = i - 720896; }
    else                 { src = Wo; dst = w16o; off = i - 851968; }
    float4 v = ((const float4*)src)[off];
    ushort4 u;
    u.x = f2bf(v.x * sc); u.y = f2bf(v.y * sc);
    u.z = f2bf(v.z * sc); u.w = f2bf(v.w * sc);
    ((ushort4*)dst)[off] = u;
  } else if (bid < 4608) {  // ---- pack rel+mask -> u8 (rd | m<<7) ----
    int i = (bid - 3584) * 256 + t;
    const int* rp = rel + i * 16;
    uint4 mu = *(const uint4*)(mask + i * 16);
    const unsigned char* mb = (const unsigned char*)&mu;
    uint4 o;
    unsigned* ow = (unsigned*)&o;
#pragma unroll
    for (int g = 0; g < 4; ++g) {
      int4 r4 = ((const int4*)rp)[g];
      unsigned b0 = ((unsigned)r4.x & 31u) | (mb[g * 4 + 0] ? 0x80u : 0u);
      unsigned b1 = ((unsigned)r4.y & 31u) | (mb[g * 4 + 1] ? 0x80u : 0u);
      unsigned b2 = ((unsigned)r4.z & 31u) | (mb[g * 4 + 2] ? 0x80u : 0u);
      unsigned b3 = ((unsigned)r4.w & 31u) | (mb[g * 4 + 3] ? 0x80u : 0u);
      ow[g] = b0 | (b1 << 8) | (b2 << 16) | (b3 << 24);
    }
    *(uint4*)(pk8 + i * 16) = o;
  } else {  // ---- wemb: Wqpw = (qpe_h @ Wq_h)/8, Wkpw = (kpe_h @ Wk_eh)/8 ----
    int bid2 = bid - 4608;
    int cc = bid2 & 7, unit = bid2 >> 3;
    int c0 = cc << 6;
    const float* emb; const float* Wsrc; unsigned short* outp; int rowbase, h;
    if (unit < 8) {
      h = unit; emb = qpe; Wsrc = Wq + (size_t)(h * 64) * 512; outp = wqp;
      rowbase = h * 32;
    } else {
      int uu = unit - 8; int e = uu >> 3; h = uu & 7;
      emb = kpe; Wsrc = Wk + (size_t)(e * 512 + h * 64) * 512; outp = wkp;
      rowbase = e * 256 + h * 32;
    }
    __shared__ float es[32][65];
    __shared__ float wsh[64][68];
    {
      int n = t >> 3, d4 = (t & 7) << 3;
      float4 v0 = *(const float4*)(emb + (size_t)n * 512 + h * 64 + d4);
      float4 v1 = *(const float4*)(emb + (size_t)n * 512 + h * 64 + d4 + 4);
      *(float4*)&es[n][d4] = v0;
      *(float4*)&es[n][d4 + 4] = v1;
    }
#pragma unroll
    for (int p = 0; p < 4; ++p) {   // 64 rows x 64 cols = 1024 float4
      int slot = t + (p << 8);
      int d = slot >> 4, c4 = (slot & 15) << 2;
      *(float4*)&wsh[d][c4] = *(const float4*)(Wsrc + (size_t)d * 512 + c0 + c4);
    }
    __syncthreads();
    const int n = t >> 3, cb = (t & 7) << 3;
    float acc[8] = {};
#pragma unroll
    for (int d = 0; d < 64; ++d) {
      float ev = es[n][d];
      float4 w0 = *(const float4*)&wsh[d][cb];
      float4 w1 = *(const float4*)&wsh[d][cb + 4];
      acc[0] = fmaf(ev, w0.x, acc[0]); acc[1] = fmaf(ev, w0.y, acc[1]);
      acc[2] = fmaf(ev, w0.z, acc[2]); acc[3] = fmaf(ev, w0.w, acc[3]);
      acc[4] = fmaf(ev, w1.x, acc[4]); acc[5] = fmaf(ev, w1.y, acc[5]);
      acc[6] = fmaf(ev, w1.z, acc[6]); acc[7] = fmaf(ev, w1.w, acc[7]);
    }
    unsigned short* orow = outp + (size_t)(rowbase + n) * 512 + c0 + cb;
#pragma unroll
    for (int j = 0; j < 8; ++j) orow[j] = f2bf(acc[j] * 0.125f);
  }
}

// ---------------------------------------------------------------------------
// projgemm_k: all three projections in ONE launch (shared A = x16, K=512).
// grid (52, 64): nx<12 -> Q (N=768: q16h | qpw16); nx<36 -> K (N=1536:
// kb16 | kpw16); else V (N=1024 -> vT16). 64x64 tile, BK=64, LDS stride 76.
// ---------------------------------------------------------------------------
__global__ __launch_bounds__(256, 4) void projgemm_k(
    const unsigned short* __restrict__ A, const unsigned short* __restrict__ w16q,
    const unsigned short* __restrict__ wqp, const unsigned short* __restrict__ w16k,
    const unsigned short* __restrict__ wkp, const unsigned short* __restrict__ w16v,
    unsigned short* __restrict__ q16h, unsigned short* __restrict__ qpw16,
    unsigned short* __restrict__ kb16, unsigned short* __restrict__ kpw16,
    unsigned short* __restrict__ vT16) {
  const int t = threadIdx.x;
  const int w = t >> 6, lane = t & 63, ln = lane & 15, qd = lane >> 4;
  const int wm = (w >> 1) << 5, wn = (w & 1) << 5;
  const int m0 = blockIdx.y << 6;
  const int nx = blockIdx.x;
  int mode, n0;
  const unsigned short* Bb;
  if (nx < 12) {
    mode = 1; n0 = nx << 6;
    Bb = (n0 < 512) ? w16q + (size_t)n0 * 512 : wqp + (size_t)(n0 - 512) * 512;
  } else if (nx < 36) {
    mode = 2; n0 = (nx - 12) << 6;
    Bb = (n0 < 1024) ? w16k + (size_t)n0 * 512 : wkp + (size_t)(n0 - 1024) * 512;
  } else {
    mode = 3; n0 = (nx - 36) << 6;
    Bb = w16v + (size_t)n0 * 512;
  }
  __shared__ unsigned short As[64 * 76];
  __shared__ unsigned short Bs[64 * 76];
  const int r0 = t >> 3, c8 = (t & 7) << 3;
  const unsigned short* ga = A + (size_t)(m0 + r0) * 512 + c8;
  const unsigned short* gb = Bb + (size_t)r0 * 512 + c8;
  const size_t half = (size_t)32 * 512;
  uint4 va0 = *(const uint4*)ga, va1 = *(const uint4*)(ga + half);
  uint4 vb0 = *(const uint4*)gb, vb1 = *(const uint4*)(gb + half);
  f32x4 z = {0.f, 0.f, 0.f, 0.f};
  f32x4 acc[2][2] = {{z, z}, {z, z}};
  for (int k0 = 0; k0 < 512; k0 += 64) {
    *(uint4*)&As[r0 * 76 + c8] = va0;
    *(uint4*)&As[(r0 + 32) * 76 + c8] = va1;
    *(uint4*)&Bs[r0 * 76 + c8] = vb0;
    *(uint4*)&Bs[(r0 + 32) * 76 + c8] = vb1;
    __syncthreads();
    if (k0 + 64 < 512) {
      va0 = *(const uint4*)(ga + k0 + 64);
      va1 = *(const uint4*)(ga + half + k0 + 64);
      vb0 = *(const uint4*)(gb + k0 + 64);
      vb1 = *(const uint4*)(gb + half + k0 + 64);
    }
#pragma unroll
    for (int kk = 0; kk < 64; kk += 32) {
      bf16x8 a0 = ldb16x8(&As[(wm + ln) * 76 + kk + qd * 8]);
      bf16x8 a1 = ldb16x8(&As[(wm + 16 + ln) * 76 + kk + qd * 8]);
      bf16x8 b0 = ldb16x8(&Bs[(wn + ln) * 76 + kk + qd * 8]);
      bf16x8 b1 = ldb16x8(&Bs[(wn + 16 + ln) * 76 + kk + qd * 8]);
      acc[0][0] = MFMA16(a0, b0, acc[0][0]);
      acc[0][1] = MFMA16(a0, b1, acc[0][1]);
      acc[1][0] = MFMA16(a1, b0, acc[1][0]);
      acc[1][1] = MFMA16(a1, b1, acc[1][1]);
    }
    __syncthreads();
  }
#pragma unroll
  for (int tm = 0; tm < 2; ++tm)
#pragma unroll
    for (int tn = 0; tn < 2; ++tn)
#pragma unroll
      for (int r = 0; r < 4; ++r) {
        int m = m0 + wm + tm * 16 + qd * 4 + r;
        int n = n0 + wn + tn * 16 + ln;
        float v = acc[tm][tn][r];
        int bb = m >> 9, s = m & 511;
        if (mode == 1) {
          if (n < 512) {
            int hh = (n >> 6) & 7, d = n & 63;
            q16h[((size_t)(bb * 8 + hh) * 512 + s) * 64 + d] = f2bf(v);
          } else {
            int n2 = n - 512, hh = n2 >> 5, nn = n2 & 31;
            qpw16[((size_t)(bb * 8 + hh) * 512 + s) * 32 + nn] = f2bf(v);
          }
        } else if (mode == 2) {
          if (n < 1024) {
            int e = n >> 9, hh = (n >> 6) & 7, d = n & 63;
            int k2 = 2 * s + e;
            kb16[((size_t)(bb * 8 + hh) * 1024 + k2) * 64 + d] = f2bf(v);
          } else {
            int n2 = n - 1024, e = n2 >> 8, hh = (n2 >> 5) & 7, nn = n2 & 31;
            int k2 = 2 * s + e;
            kpw16[((size_t)(bb * 8 + hh) * 1024 + k2) * 32 + nn] = f2bf(v);
          }
        } else {
          int e = n >> 9, hh = (n >> 6) & 7, d = n & 63;
          int k2 = 2 * s + e;
          vT16[((size_t)(bb * 8 + hh) * 64 + d) * 1024 + k2] = f2bf(v);
        }
      }
}

// ---------------------------------------------------------------------------
// ogemm_k: out = attn16 @ w16o^T, fp32 out. 64x64 tile, BK=64, stride 76.
// ---------------------------------------------------------------------------
__global__ __launch_bounds__(256, 4) void ogemm_k(
    const unsigned short* __restrict__ A, const unsigned short* __restrict__ B,
    float* __restrict__ C) {
  const int t = threadIdx.x;
  const int w = t >> 6, lane = t & 63, ln = lane & 15, qd = lane >> 4;
  const int wm = (w >> 1) << 5, wn = (w & 1) << 5;
  const int m0 = blockIdx.y << 6, n0 = blockIdx.x << 6;
  __shared__ unsigned short As[64 * 76];
  __shared__ unsigned short Bs[64 * 76];
  const int r0 = t >> 3, c8 = (t & 7) << 3;
  const unsigned short* ga = A + (size_t)(m0 + r0) * 512 + c8;
  const unsigned short* gb = B + (size_t)(n0 + r0) * 512 + c8;
  const size_t half = (size_t)32 * 512;
  uint4 va0 = *(const uint4*)ga, va1 = *(const uint4*)(ga + half);
  uint4 vb0 = *(const uint4*)gb, vb1 = *(const uint4*)(gb + half);
  f32x4 z = {0.f, 0.f, 0.f, 0.f};
  f32x4 acc[2][2] = {{z, z}, {z, z}};
  for (int k0 = 0; k0 < 512; k0 += 64) {
    *(uint4*)&As[r0 * 76 + c8] = va0;
    *(uint4*)&As[(r0 + 32) * 76 + c8] = va1;
    *(uint4*)&Bs[r0 * 76 + c8] = vb0;
    *(uint4*)&Bs[(r0 + 32) * 76 + c8] = vb1;
    __syncthreads();
    if (k0 + 64 < 512) {
      va0 = *(const uint4*)(ga + k0 + 64);
      va1 = *(const uint4*)(ga + half + k0 + 64);
      vb0 = *(const uint4*)(gb + k0 + 64);
      vb1 = *(const uint4*)(gb + half + k0 + 64);
    }
#pragma unroll
    for (int kk = 0; kk < 64; kk += 32) {
      bf16x8 a0 = ldb16x8(&As[(wm + ln) * 76 + kk + qd * 8]);
      bf16x8 a1 = ldb16x8(&As[(wm + 16 + ln) * 76 + kk + qd * 8]);
      bf16x8 b0 = ldb16x8(&Bs[(wn + ln) * 76 + kk + qd * 8]);
      bf16x8 b1 = ldb16x8(&Bs[(wn + 16 + ln) * 76 + kk + qd * 8]);
      acc[0][0] = MFMA16(a0, b0, acc[0][0]);
      acc[0][1] = MFMA16(a0, b1, acc[0][1]);
      acc[1][0] = MFMA16(a1, b0, acc[1][0]);
      acc[1][1] = MFMA16(a1, b1, acc[1][1]);
    }
    __syncthreads();
  }
#pragma unroll
  for (int tm = 0; tm < 2; ++tm)
#pragma unroll
    for (int tn = 0; tn < 2; ++tn)
#pragma unroll
      for (int r = 0; r < 4; ++r) {
        int m = m0 + wm + tm * 16 + qd * 4 + r;
        int n = n0 + wn + tn * 16 + ln;
        C[(size_t)m * 512 + n] = acc[tm][tn][r];
      }
}

// ---------------------------------------------------------------------------
// attn7_k: MFMA attention. vdw histogram in u32 fixed-point (Q=2^12, native
// ds_add_u32, stride 33 => banks spread); pbuf stride 68 (clean 2-way b128);
// LDS 49920 B. XCD-affine grid (bid%8==b), split-K wave groups.
// ---------------------------------------------------------------------------
__global__ __launch_bounds__(512, 6) void attn7_k(
    const unsigned short* __restrict__ q16h, const unsigned short* __restrict__ kb16,
    const unsigned short* __restrict__ vT16, const unsigned short* __restrict__ qpw16,
    const unsigned short* __restrict__ kpw16, const unsigned char* __restrict__ pk8,
    const float* __restrict__ v_emb, unsigned short* __restrict__ attn16) {
  const int bid = blockIdx.x;
  const int b = bid & 7;                 // XCD-affine
  const int h = (bid >> 3) & 7;
  const int qb = ((bid >> 6) & 7) << 6;
  const int t = threadIdx.x;
  const int w = t >> 6, g = w >> 2, ws4 = w & 3;
  const int lane = t & 63, ln = lane & 15, qd = lane >> 4;

  __shared__ __align__(16) char smem[49920];
  unsigned char*  pkt  = (unsigned char*)smem;              // 2 x (64x80) u8
  unsigned short* kpws = (unsigned short*)(smem + 10240);   // 2 x (64x36) u16
  unsigned short* q32s = (unsigned short*)(smem + 19456);   // 64x36 u16
  unsigned short* pbuf = (unsigned short*)(smem + 24064);   // 8 x (16x68) u16
  unsigned*       vdwm = (unsigned*)(smem + 41472);         // 4 x (16x33) u32
  // endgame aliases (source regions dead by then):
  float*          accbuf = (float*)smem;                    // 4 x (16x68) f
  unsigned short* vest   = (unsigned short*)(smem + 24064); // 64x40 u16
  unsigned short* vdwb   = (unsigned short*)(smem + 29184); // 4 x (16x40) u16

  for (int i = t; i < 4 * 16 * 33; i += 512) vdwm[i] = 0u;
  if (t < 256) {  // q32s: 64 q x 32 n bf16, straight copy
    int row = t >> 2, c8 = (t & 3) << 3;
    *(uint4*)&q32s[row * 36 + c8] =
        *(const uint4*)(qpw16 + ((size_t)((b * 8 + h) * 512 + qb) + row) * 32 + c8);
  }
  const unsigned short* kbase = kb16 + (size_t)(b * 8 + h) * 65536;
  const unsigned short* vbase = vT16 + (size_t)(b * 8 + h) * 65536;
  bf16x8 aQ[2];
  {
    const unsigned short* qsrc =
        q16h + ((size_t)((b * 8 + h) * 512 + qb + ws4 * 16 + ln)) * 64;
    aQ[0] = ldb16x8(qsrc + qd * 8);
    aQ[1] = ldb16x8(qsrc + 32 + qd * 8);
  }
  f32x4 z = {0.f, 0.f, 0.f, 0.f};
  f32x4 acc[4] = {z, z, z, z};

  // staging (squad gg = t>>8 stages kt-half gg)
  const int u = t & 255, gg = t >> 8;
  const int qr = u >> 2, cg = (u & 3) << 4;
  const int kc8 = (u & 3) << 3;
  const unsigned char* pks = pk8 + ((size_t)(b * 512 + qb + qr)) * 1024 + (gg << 9);
  const unsigned short* kps =
      kpw16 + ((size_t)((b * 8 + h) * 1024) + (gg << 9) + qr) * 32 + kc8;
  unsigned char* pt_w = pkt + gg * 5120 + qr * 80 + cg;
  unsigned short* kp_w = kpws + gg * 2304 + qr * 36 + kc8;

  uint4 pv = *(const uint4*)(pks + cg);
  uint4 kv = *(const uint4*)kps;

  for (int kti = 0; kti < 8; ++kti) {
    *(uint4*)pt_w = pv;
    *(uint4*)kp_w = kv;
    __syncthreads();
    if (kti < 7) {
      pv = *(const uint4*)(pks + ((kti + 1) << 6) + cg);
      kv = *(const uint4*)(kps + ((size_t)(kti + 1) << 11));
    }
    const int kt0 = (kti + g * 8) << 6;

    // ---- QK^T ----
    f32x4 sc4[4];
#pragma unroll
    for (int t4 = 0; t4 < 4; ++t4) {
      f32x4 c = z;
      c = MFMA16(aQ[0], ldb16x8(kbase + (size_t)(kt0 + t4 * 16 + ln) * 64 + qd * 8), c);
      c = MFMA16(aQ[1], ldb16x8(kbase + (size_t)(kt0 + t4 * 16 + ln) * 64 + 32 + qd * 8), c);
      sc4[t4] = c;
    }

    // ---- bias + mask + exp; u32 vdw scatter; P -> pbuf ----
    unsigned char* pt_ = pkt + g * 5120;
    unsigned short* kp_ = kpws + g * 2304;
#pragma unroll
    for (int r = 0; r < 4; ++r) {
#pragma unroll
      for (int t4 = 0; t4 < 4; ++t4) {
        int row_l = ws4 * 16 + qd * 4 + r;
        int kl = t4 * 16 + ln;
        unsigned um = pt_[row_l * 80 + kl];
        int rd = um & 31;
        float s = sc4[t4][r] + b2f(q32s[row_l * 36 + rd]) + b2f(kp_[kl * 36 + rd]);
        float p = (um & 0x80u) ? 0.f : __expf(s);
        atomicAdd(&vdwm[ws4 * 528 + (qd * 4 + r) * 33 + rd],
                  (unsigned)(p * 4096.0f));                 // Q = 2^12, ds_add_u32
        pbuf[w * 1088 + (qd * 4 + r) * 68 + kl] = f2bf(p);
      }
    }

    // ---- PV ----
    bf16x8 a0 = ldb16x8(&pbuf[w * 1088 + ln * 68 + qd * 8]);
    bf16x8 a1 = ldb16x8(&pbuf[w * 1088 + ln * 68 + 32 + qd * 8]);
#pragma unroll
    for (int dt = 0; dt < 4; ++dt) {
      acc[dt] = MFMA16(a0, ldb16x8(vbase + (size_t)(dt * 16 + ln) * 1024 + kt0 + qd * 8), acc[dt]);
      acc[dt] = MFMA16(a1, ldb16x8(vbase + (size_t)(dt * 16 + ln) * 1024 + kt0 + 32 + qd * 8), acc[dt]);
    }
    __syncthreads();
  }

  // ---- endgame ----
  if (t < 256) {
    int n = t >> 3, d0 = (t & 7) << 3;
    const float* src = v_emb + ((size_t)n << 9) + (h << 6) + d0;
    float4 f0 = *(const float4*)src;
    float4 f1 = *(const float4*)(src + 4);
    vest[(d0 + 0) * 40 + n] = f2bf(f0.x); vest[(d0 + 1) * 40 + n] = f2bf(f0.y);
    vest[(d0 + 2) * 40 + n] = f2bf(f0.z); vest[(d0 + 3) * 40 + n] = f2bf(f0.w);
    vest[(d0 + 4) * 40 + n] = f2bf(f1.x); vest[(d0 + 5) * 40 + n] = f2bf(f1.y);
    vest[(d0 + 6) * 40 + n] = f2bf(f1.z); vest[(d0 + 7) * 40 + n] = f2bf(f1.w);
  } else {
    int row = lane >> 2, n0 = (lane & 3) << 3;
    float vv[8];
#pragma unroll
    for (int j = 0; j < 8; ++j)
      vv[j] = (float)vdwm[ws4 * 528 + row * 33 + n0 + j] * (1.0f / 4096.0f);
    ushort4 u0, u1;
    u0.x = f2bf(vv[0]); u0.y = f2bf(vv[1]); u0.z = f2bf(vv[2]); u0.w = f2bf(vv[3]);
    u1.x = f2bf(vv[4]); u1.y = f2bf(vv[5]); u1.z = f2bf(vv[6]); u1.w = f2bf(vv[7]);
    *(ushort4*)&vdwb[ws4 * 640 + row * 40 + n0] = u0;
    *(ushort4*)&vdwb[ws4 * 640 + row * 40 + n0 + 4] = u1;
  }
  __syncthreads();

  if (g == 1) {  // vdw @ v_emb into g1 partial, publish partial O
    bf16x8 av = ldb16x8(&vdwb[ws4 * 640 + ln * 40 + qd * 8]);
#pragma unroll
    for (int dt = 0; dt < 4; ++dt)
      acc[dt] = MFMA16(av, ldb16x8(&vest[(dt * 16 + ln) * 40 + qd * 8]), acc[dt]);
#pragma unroll
    for (int r = 0; r < 4; ++r)
#pragma unroll
      for (int dt = 0; dt < 4; ++dt)
        accbuf[ws4 * 1088 + (qd * 4 + r) * 68 + dt * 16 + ln] = acc[dt][r];
  }
  __syncthreads();

  if (g == 0) {  // combine, normalize, store bf16
    float inv[4];
#pragma unroll
    for (int r = 0; r < 4; ++r) {
      unsigned long long lu = 0ull;
#pragma unroll
      for (int n = 0; n < 32; ++n)
        lu += vdwm[ws4 * 528 + (qd * 4 + r) * 33 + n];
      inv[r] = 4096.0f / (float)lu;
    }
    unsigned short* obase =
        attn16 + ((size_t)(b * 512 + qb + ws4 * 16 + qd * 4)) * 512 + (h << 6);
#pragma unroll
    for (int r = 0; r < 4; ++r)
#pragma unroll
      for (int dt = 0; dt < 4; ++dt) {
        float v = (acc[dt][r] + accbuf[ws4 * 1088 + (qd * 4 + r) * 68 + dt * 16 + ln]) * inv[r];
        obase[(size_t)r * 512 + dt * 16 + ln] = f2bf(v);
      }
  }
}

// ---------------------------------------------------------------------------
extern "C" void kernel_launch(void* const* d_in, const int* in_sizes, int n_in,
                              void* d_out, int out_size, void* d_ws, size_t ws_size,
                              hipStream_t stream) {
  const float* x = (const float*)d_in[0];
  const int* rel = (const int*)d_in[1];
  const unsigned char* mask = (const unsigned char*)d_in[2];
  const float* qpe = (const float*)d_in[3];
  const float* kpe = (const float*)d_in[4];
  const float* vpe = (const float*)d_in[5];
  const float* Wq = (const float*)d_in[6];
  const float* Wk = (const float*)d_in[7];
  const float* Wv = (const float*)d_in[8];
  const float* Wo = (const float*)d_in[9];
  float* out = (float*)d_out;

  unsigned short* u = (unsigned short*)d_ws;
  unsigned short* x16    = u;                    // 2,097,152
  unsigned short* w16q   = x16 + 2097152;        //   262,144
  unsigned short* w16k   = w16q + 262144;        //   524,288
  unsigned short* w16v   = w16k + 524288;        //   524,288
  unsigned short* w16o   = w16v + 524288;        //   262,144
  unsigned short* wqp16  = w16o + 262144;        //   131,072
  unsigned short* wkp16  = wqp16 + 131072;       //   262,144
  unsigned short* q16h   = wkp16 + 262144;       // 2,097,152
  unsigned short* qpw16  = q16h + 2097152;       // 1,048,576
  unsigned short* kb16   = qpw16 + 1048576;      // 4,194,304
  unsigned short* kpw16  = kb16 + 4194304;       // 2,097,152
  unsigned short* vT16   = kpw16 + 2097152;      // 4,194,304
  unsigned short* attn16 = vT16 + 4194304;       // 2,097,152
  unsigned char* pk8 = (unsigned char*)(attn16 + 2097152);  // 4 MB -> ~44 MB

  prep_k<<<4800, 256, 0, stream>>>(x, rel, mask, qpe, kpe, Wq, Wk, Wv, Wo,
                                   x16, w16q, w16k, w16v, w16o, wqp16, wkp16, pk8);
  projgemm_k<<<dim3(52, 64), 256, 0, stream>>>(x16, w16q, wqp16, w16k, wkp16, w16v,
                                               q16h, qpw16, kb16, kpw16, vT16);
  attn7_k<<<512, 512, 0, stream>>>(q16h, kb16, vT16, qpw16, kpw16, pk8, vpe, attn16);
  ogemm_k<<<dim3(8, 64), 256, 0, stream>>>(attn16, w16o, out);
}

// Round 10
// 221.286 us; speedup vs baseline: 1.4298x; 1.4298x over previous
//
#include <hip/hip_runtime.h>
#include <math.h>

typedef __attribute__((ext_vector_type(8))) short bf16x8;
typedef __attribute__((ext_vector_type(4))) float f32x4;
#define MFMA16(a, b, c) __builtin_amdgcn_mfma_f32_16x16x32_bf16(a, b, c, 0, 0, 0)

__device__ __forceinline__ unsigned short f2bf(float f) {
  unsigned u = __float_as_uint(f);
  return (unsigned short)((u + 0x7fffu + ((u >> 16) & 1u)) >> 16);  // RNE
}
__device__ __forceinline__ float b2f(unsigned short u) {
  return __uint_as_float((unsigned)u << 16);
}
__device__ __forceinline__ bf16x8 ldb16x8(const unsigned short* p) {
  union { uint4 u; bf16x8 s; } cv;
  cv.u = *(const uint4*)p;
  return cv.s;
}

// ---------------------------------------------------------------------------
// fp32 -> bf16 conversions. Wq is pre-scaled by 0.125 (exact exponent shift)
// so QK^T comes out of the attention MFMA already divided by 8.
// ---------------------------------------------------------------------------
__global__ __launch_bounds__(256) void cvt5_k(
    const float* __restrict__ x, const float* __restrict__ wq,
    const float* __restrict__ wk, const float* __restrict__ wv,
    const float* __restrict__ wo, unsigned short* __restrict__ x16,
    unsigned short* __restrict__ w16q, unsigned short* __restrict__ w16k,
    unsigned short* __restrict__ w16v, unsigned short* __restrict__ w16o) {
  int i = blockIdx.x * 256 + threadIdx.x;
  const float* src; unsigned short* dst; int off; float sc = 1.f;
  if (i < 524288)      { src = x;  dst = x16;  off = i; }
  else if (i < 589824) { src = wq; dst = w16q; off = i - 524288; sc = 0.125f; }
  else if (i < 720896) { src = wk; dst = w16k; off = i - 589824; }
  else if (i < 851968) { src = wv; dst = w16v; off = i - 720896; }
  else                 { src = wo; dst = w16o; off = i - 851968; }
  float4 v = ((const float4*)src)[off];
  ushort4 u;
  u.x = f2bf(v.x * sc); u.y = f2bf(v.y * sc);
  u.z = f2bf(v.z * sc); u.w = f2bf(v.w * sc);
  ((ushort4*)dst)[off] = u;
}

// ---------------------------------------------------------------------------
// Pack rel (int32 0..31) + mask (u8) -> u8 (rd | m<<7).
// ---------------------------------------------------------------------------
__global__ __launch_bounds__(256) void pack_k(const int* __restrict__ rel,
                                              const unsigned char* __restrict__ mask,
                                              unsigned char* __restrict__ pk8) {
  int i = blockIdx.x * 256 + threadIdx.x;
  const int* rp = rel + i * 16;
  uint4 mu = *(const uint4*)(mask + i * 16);
  const unsigned char* mb = (const unsigned char*)&mu;
  uint4 o;
  unsigned* ow = (unsigned*)&o;
#pragma unroll
  for (int g = 0; g < 4; ++g) {
    int4 r4 = ((const int4*)rp)[g];
    unsigned b0 = ((unsigned)r4.x & 31u) | (mb[g * 4 + 0] ? 0x80u : 0u);
    unsigned b1 = ((unsigned)r4.y & 31u) | (mb[g * 4 + 1] ? 0x80u : 0u);
    unsigned b2 = ((unsigned)r4.z & 31u) | (mb[g * 4 + 2] ? 0x80u : 0u);
    unsigned b3 = ((unsigned)r4.w & 31u) | (mb[g * 4 + 3] ? 0x80u : 0u);
    ow[g] = b0 | (b1 << 8) | (b2 << 16) | (b3 << 24);
  }
  *(uint4*)(pk8 + i * 16) = o;
}

// ---------------------------------------------------------------------------
// Fold pos-embeddings into the projection weights:
//   Wqpw[h*32+n][c]        = 1/8 * sum_d qpe[n][h*64+d] * Wq[h*64+d][c]
//   Wkpw[e*256+h*32+n][c]  = 1/8 * sum_d kpe[n][h*64+d] * Wk[e*512+h*64+d][c]
// ---------------------------------------------------------------------------
__global__ __launch_bounds__(256) void wemb_k(
    const float* __restrict__ qpe, const float* __restrict__ kpe,
    const float* __restrict__ Wq, const float* __restrict__ Wk,
    unsigned short* __restrict__ wqp, unsigned short* __restrict__ wkp) {
  const int bid = blockIdx.x;
  const int cc = bid & 3, unit = bid >> 2;
  const int c0 = cc << 7;
  const int t = threadIdx.x;
  const float* emb; const float* Wsrc; unsigned short* outp; int rowbase, h;
  if (unit < 8) {
    h = unit; emb = qpe; Wsrc = Wq + (size_t)(h * 64) * 512; outp = wqp; rowbase = h * 32;
  } else {
    int u = unit - 8; int e = u >> 3; h = u & 7;
    emb = kpe; Wsrc = Wk + (size_t)(e * 512 + h * 64) * 512; outp = wkp;
    rowbase = e * 256 + h * 32;
  }
  __shared__ float es[32][65];
  __shared__ float wsh[64][132];
  {
    int n = t >> 3, d4 = (t & 7) << 3;
    float4 v0 = *(const float4*)(emb + (size_t)n * 512 + h * 64 + d4);
    float4 v1 = *(const float4*)(emb + (size_t)n * 512 + h * 64 + d4 + 4);
    *(float4*)&es[n][d4] = v0;
    *(float4*)&es[n][d4 + 4] = v1;
  }
#pragma unroll
  for (int p = 0; p < 8; ++p) {
    int slot = t + (p << 8);
    int d = slot >> 5, c4 = (slot & 31) << 2;
    *(float4*)&wsh[d][c4] = *(const float4*)(Wsrc + (size_t)d * 512 + c0 + c4);
  }
  __syncthreads();
  const int n = t >> 3, cb = (t & 7) << 4;
  float acc[16] = {};
#pragma unroll
  for (int d = 0; d < 64; ++d) {
    float ev = es[n][d];
    float4 w0 = *(const float4*)&wsh[d][cb];
    float4 w1 = *(const float4*)&wsh[d][cb + 4];
    float4 w2 = *(const float4*)&wsh[d][cb + 8];
    float4 w3 = *(const float4*)&wsh[d][cb + 12];
    acc[0] = fmaf(ev, w0.x, acc[0]);   acc[1] = fmaf(ev, w0.y, acc[1]);
    acc[2] = fmaf(ev, w0.z, acc[2]);   acc[3] = fmaf(ev, w0.w, acc[3]);
    acc[4] = fmaf(ev, w1.x, acc[4]);   acc[5] = fmaf(ev, w1.y, acc[5]);
    acc[6] = fmaf(ev, w1.z, acc[6]);   acc[7] = fmaf(ev, w1.w, acc[7]);
    acc[8] = fmaf(ev, w2.x, acc[8]);   acc[9] = fmaf(ev, w2.y, acc[9]);
    acc[10] = fmaf(ev, w2.z, acc[10]); acc[11] = fmaf(ev, w2.w, acc[11]);
    acc[12] = fmaf(ev, w3.x, acc[12]); acc[13] = fmaf(ev, w3.y, acc[13]);
    acc[14] = fmaf(ev, w3.z, acc[14]); acc[15] = fmaf(ev, w3.w, acc[15]);
  }
  unsigned short* orow = outp + (size_t)(rowbase + n) * 512 + c0 + cb;
#pragma unroll
  for (int j = 0; j < 16; ++j) orow[j] = f2bf(acc[j] * 0.125f);
}

// ---------------------------------------------------------------------------
// bf16 MFMA GEMM, 64x64 tile, BK=64, LDS stride 72, register-pipelined staging.
// B = concat(B1[0:nsplit), B2[nsplit:N)) row-major [N][K].
// MODE 0: fp32 out1 | 1: q16h/qpw16 | 2: kb16/kpw16 | 3: vT16
// ---------------------------------------------------------------------------
template <int MODE>
__global__ __launch_bounds__(256, 4) void gemm16_k(
    const unsigned short* __restrict__ A, const unsigned short* __restrict__ B1,
    const unsigned short* __restrict__ B2, void* __restrict__ out1,
    void* __restrict__ out2, int M, int N, int K, int nsplit) {
  const int t = threadIdx.x;
  const int w = t >> 6, lane = t & 63, ln = lane & 15, qd = lane >> 4;
  const int wm = (w >> 1) << 5, wn = (w & 1) << 5;
  const int m0 = blockIdx.y << 6, n0 = blockIdx.x << 6;
  __shared__ unsigned short As[64 * 72];
  __shared__ unsigned short Bs[64 * 72];
  const bool reg1 = (n0 < nsplit);
  const unsigned short* Bb =
      reg1 ? B1 + (size_t)n0 * K : B2 + (size_t)(n0 - nsplit) * K;
  const int r0 = t >> 3, c8 = (t & 7) << 3;
  const unsigned short* ga = A + (size_t)(m0 + r0) * K + c8;
  const unsigned short* gb = Bb + (size_t)r0 * K + c8;
  const size_t half = (size_t)32 * K;
  uint4 va0 = *(const uint4*)ga, va1 = *(const uint4*)(ga + half);
  uint4 vb0 = *(const uint4*)gb, vb1 = *(const uint4*)(gb + half);
  f32x4 z = {0.f, 0.f, 0.f, 0.f};
  f32x4 acc[2][2] = {{z, z}, {z, z}};
  for (int k0 = 0; k0 < K; k0 += 64) {
    *(uint4*)&As[r0 * 72 + c8] = va0;
    *(uint4*)&As[(r0 + 32) * 72 + c8] = va1;
    *(uint4*)&Bs[r0 * 72 + c8] = vb0;
    *(uint4*)&Bs[(r0 + 32) * 72 + c8] = vb1;
    __syncthreads();
    if (k0 + 64 < K) {
      va0 = *(const uint4*)(ga + k0 + 64);
      va1 = *(const uint4*)(ga + half + k0 + 64);
      vb0 = *(const uint4*)(gb + k0 + 64);
      vb1 = *(const uint4*)(gb + half + k0 + 64);
    }
#pragma unroll
    for (int kk = 0; kk < 64; kk += 32) {
      bf16x8 a0 = ldb16x8(&As[(wm + ln) * 72 + kk + qd * 8]);
      bf16x8 a1 = ldb16x8(&As[(wm + 16 + ln) * 72 + kk + qd * 8]);
      bf16x8 b0 = ldb16x8(&Bs[(wn + ln) * 72 + kk + qd * 8]);
      bf16x8 b1 = ldb16x8(&Bs[(wn + 16 + ln) * 72 + kk + qd * 8]);
      acc[0][0] = MFMA16(a0, b0, acc[0][0]);
      acc[0][1] = MFMA16(a0, b1, acc[0][1]);
      acc[1][0] = MFMA16(a1, b0, acc[1][0]);
      acc[1][1] = MFMA16(a1, b1, acc[1][1]);
    }
    __syncthreads();
  }
#pragma unroll
  for (int tm = 0; tm < 2; ++tm)
#pragma unroll
    for (int tn = 0; tn < 2; ++tn)
#pragma unroll
      for (int r = 0; r < 4; ++r) {
        int m = m0 + wm + tm * 16 + qd * 4 + r;
        int n = n0 + wn + tn * 16 + ln;
        float v = acc[tm][tn][r];
        int bb = m >> 9, s = m & 511;
        if (MODE == 0) {
          ((float*)out1)[(size_t)m * N + n] = v;
        } else if (MODE == 3) {
          int e = n >> 9, hh = (n >> 6) & 7, d = n & 63;
          int k2 = 2 * s + e;
          ((unsigned short*)out1)[((size_t)(bb * 8 + hh) * 64 + d) * 1024 + k2] = f2bf(v);
        } else if (MODE == 1) {
          if (reg1) {
            int hh = (n >> 6) & 7, d = n & 63;
            ((unsigned short*)out1)[((size_t)(bb * 8 + hh) * 512 + s) * 64 + d] = f2bf(v);
          } else {
            int n2 = n - 512, hh = n2 >> 5, nn = n2 & 31;
            ((unsigned short*)out2)[((size_t)(bb * 8 + hh) * 512 + s) * 32 + nn] = f2bf(v);
          }
        } else {  // MODE 2
          if (reg1) {
            int e = n >> 9, hh = (n >> 6) & 7, d = n & 63;
            int k2 = 2 * s + e;
            ((unsigned short*)out1)[((size_t)(bb * 8 + hh) * 1024 + k2) * 64 + d] = f2bf(v);
          } else {
            int n2 = n - 1024, e = n2 >> 8, hh = (n2 >> 5) & 7, nn = n2 & 31;
            int k2 = 2 * s + e;
            ((unsigned short*)out2)[((size_t)(bb * 8 + hh) * 1024 + k2) * 32 + nn] = f2bf(v);
          }
        }
      }
}

// ---------------------------------------------------------------------------
// attn8_k: R8's attn6 with ONE delta — vdw histogram u64-stride-36 -> u32
// fixed-point Q=2^12, row stride 33 (one bank per ds_add_u32, rows spread
// across banks). Targets the measured 8.6M SQ_LDS_BANK_CONFLICT.
// ---------------------------------------------------------------------------
__global__ __launch_bounds__(512, 4) void attn8_k(
    const unsigned short* __restrict__ q16h, const unsigned short* __restrict__ kb16,
    const unsigned short* __restrict__ vT16, const unsigned short* __restrict__ qpw16,
    const unsigned short* __restrict__ kpw16, const unsigned char* __restrict__ pk8,
    const float* __restrict__ v_emb, unsigned short* __restrict__ attn16) {
  const int bid = blockIdx.x;
  const int b = bid & 7;                 // XCD-affine: bid%8 == b
  const int h = (bid >> 3) & 7;
  const int qb = ((bid >> 6) & 7) << 6;
  const int t = threadIdx.x;
  const int w = t >> 6;
  const int g = w >> 2;
  const int ws4 = w & 3;
  const int lane = t & 63;
  const int ln = lane & 15;
  const int qd = lane >> 4;

  __shared__ __align__(16) char smem[50944];
  unsigned char*  pkt  = (unsigned char*)smem;                // 2 x (64x80) u8
  unsigned short* kpws = (unsigned short*)(smem + 10240);     // 2 x (64x36) u16
  unsigned short* q32s = (unsigned short*)(smem + 19456);     // 64x36 u16
  unsigned short* pbuf = (unsigned short*)(smem + 24064);     // 8 x (16x72) u16
  unsigned*       vdwm = (unsigned*)(smem + 42496);           // 4 x (16x33) u32
  // endgame aliases (source regions dead by then):
  float*          accbuf = (float*)smem;                      // 4 x (16x68) f
  unsigned short* vest   = (unsigned short*)(smem + 24064);   // 64x40 u16
  unsigned short* vdwb   = (unsigned short*)(smem + 29184);   // 4 x (16x40) u16

  for (int i = t; i < 4 * 16 * 33; i += 512) vdwm[i] = 0u;
  if (t < 256) {  // q32s: 64 q x 32 n bf16, straight copy
    int row = t >> 2, c8 = (t & 3) << 3;
    *(uint4*)&q32s[row * 36 + c8] =
        *(const uint4*)(qpw16 + ((size_t)((b * 8 + h) * 512 + qb) + row) * 32 + c8);
  }
  const unsigned short* kbase = kb16 + (size_t)(b * 8 + h) * 65536;
  const unsigned short* vbase = vT16 + (size_t)(b * 8 + h) * 65536;
  bf16x8 aQ[2];
  {
    const unsigned short* qsrc =
        q16h + ((size_t)((b * 8 + h) * 512 + qb + ws4 * 16 + ln)) * 64;
    aQ[0] = ldb16x8(qsrc + qd * 8);
    aQ[1] = ldb16x8(qsrc + 32 + qd * 8);
  }
  f32x4 z = {0.f, 0.f, 0.f, 0.f};
  f32x4 acc[4] = {z, z, z, z};

  // staging addresses (thread-fixed): squad gg = t>>8 stages for kt-half gg
  const int u = t & 255, gg = t >> 8;
  const int qr = u >> 2, cg = (u & 3) << 4;        // pkt slot (bytes)
  const int kc8 = (u & 3) << 3;                    // kpw slot (u16)
  const unsigned char* pks = pk8 + ((size_t)(b * 512 + qb + qr)) * 1024 + (gg << 9);
  const unsigned short* kps =
      kpw16 + ((size_t)((b * 8 + h) * 1024) + (gg << 9) + qr) * 32 + kc8;
  unsigned char* pt_w = pkt + gg * 5120 + qr * 80 + cg;
  unsigned short* kp_w = kpws + gg * 2304 + qr * 36 + kc8;

  uint4 pv = *(const uint4*)(pks + cg);
  uint4 kv = *(const uint4*)kps;

  for (int kti = 0; kti < 8; ++kti) {
    *(uint4*)pt_w = pv;
    *(uint4*)kp_w = kv;
    __syncthreads();
    if (kti < 7) {  // prefetch next kt's staging under the MFMA work
      pv = *(const uint4*)(pks + ((kti + 1) << 6) + cg);
      kv = *(const uint4*)(kps + ((size_t)(kti + 1) << 11));   // (kti+1)*64*32
    }
    const int kt0 = (kti + g * 8) << 6;

    // ---- QK^T: B-frags straight from global (same-XCD L2) ----
    f32x4 sc4[4];
#pragma unroll
    for (int t4 = 0; t4 < 4; ++t4) {
      f32x4 c = z;
      c = MFMA16(aQ[0], ldb16x8(kbase + (size_t)(kt0 + t4 * 16 + ln) * 64 + qd * 8), c);
      c = MFMA16(aQ[1], ldb16x8(kbase + (size_t)(kt0 + t4 * 16 + ln) * 64 + 32 + qd * 8), c);
      sc4[t4] = c;
    }

    // ---- bias + mask + exp; u32 vdw scatter (Q=2^12); P -> pbuf ----
    unsigned char* pt_ = pkt + g * 5120;
    unsigned short* kp_ = kpws + g * 2304;
#pragma unroll
    for (int r = 0; r < 4; ++r) {
#pragma unroll
      for (int t4 = 0; t4 < 4; ++t4) {
        int row_l = ws4 * 16 + qd * 4 + r;
        int kl = t4 * 16 + ln;
        unsigned um = pt_[row_l * 80 + kl];
        int rd = um & 31;
        float s = sc4[t4][r] + b2f(q32s[row_l * 36 + rd]) + b2f(kp_[kl * 36 + rd]);
        float p = (um & 0x80u) ? 0.f : __expf(s);
        atomicAdd(&vdwm[ws4 * 528 + (qd * 4 + r) * 33 + rd],
                  (unsigned)(p * 4096.0f));                   // native ds_add_u32
        pbuf[w * 1152 + (qd * 4 + r) * 72 + kl] = f2bf(p);
      }
    }

    // ---- PV: O += P(16x64) @ V(64x64) ----
    bf16x8 a0 = ldb16x8(&pbuf[w * 1152 + ln * 72 + qd * 8]);
    bf16x8 a1 = ldb16x8(&pbuf[w * 1152 + ln * 72 + 32 + qd * 8]);
#pragma unroll
    for (int dt = 0; dt < 4; ++dt) {
      acc[dt] = MFMA16(a0, ldb16x8(vbase + (size_t)(dt * 16 + ln) * 1024 + kt0 + qd * 8), acc[dt]);
      acc[dt] = MFMA16(a1, ldb16x8(vbase + (size_t)(dt * 16 + ln) * 1024 + kt0 + 32 + qd * 8), acc[dt]);
    }
    __syncthreads();
  }

  // ---- endgame: vest staged by g0 threads, vdwb built by g1 waves ----
  if (t < 256) {
    int n = t >> 3, d0 = (t & 7) << 3;
    const float* src = v_emb + ((size_t)n << 9) + (h << 6) + d0;
    float4 f0 = *(const float4*)src;
    float4 f1 = *(const float4*)(src + 4);
    vest[(d0 + 0) * 40 + n] = f2bf(f0.x); vest[(d0 + 1) * 40 + n] = f2bf(f0.y);
    vest[(d0 + 2) * 40 + n] = f2bf(f0.z); vest[(d0 + 3) * 40 + n] = f2bf(f0.w);
    vest[(d0 + 4) * 40 + n] = f2bf(f1.x); vest[(d0 + 5) * 40 + n] = f2bf(f1.y);
    vest[(d0 + 6) * 40 + n] = f2bf(f1.z); vest[(d0 + 7) * 40 + n] = f2bf(f1.w);
  } else {
    int row = lane >> 2, n0 = (lane & 3) << 3;
    float vv[8];
#pragma unroll
    for (int j = 0; j < 8; ++j)
      vv[j] = (float)vdwm[ws4 * 528 + row * 33 + n0 + j] * (1.0f / 4096.0f);
    ushort4 u0, u1;
    u0.x = f2bf(vv[0]); u0.y = f2bf(vv[1]); u0.z = f2bf(vv[2]); u0.w = f2bf(vv[3]);
    u1.x = f2bf(vv[4]); u1.y = f2bf(vv[5]); u1.z = f2bf(vv[6]); u1.w = f2bf(vv[7]);
    *(ushort4*)&vdwb[ws4 * 640 + row * 40 + n0] = u0;
    *(ushort4*)&vdwb[ws4 * 640 + row * 40 + n0 + 4] = u1;
  }
  __syncthreads();

  if (g == 1) {
    bf16x8 av = ldb16x8(&vdwb[ws4 * 640 + ln * 40 + qd * 8]);
#pragma unroll
    for (int dt = 0; dt < 4; ++dt)
      acc[dt] = MFMA16(av, ldb16x8(&vest[(dt * 16 + ln) * 40 + qd * 8]), acc[dt]);
#pragma unroll
    for (int r = 0; r < 4; ++r)
#pragma unroll
      for (int dt = 0; dt < 4; ++dt)
        accbuf[ws4 * 1088 + (qd * 4 + r) * 68 + dt * 16 + ln] = acc[dt][r];
  }
  __syncthreads();

  if (g == 0) {
    float inv[4];
#pragma unroll
    for (int r = 0; r < 4; ++r) {
      unsigned long long lu = 0ull;
#pragma unroll
      for (int n = 0; n < 32; ++n)
        lu += vdwm[ws4 * 528 + (qd * 4 + r) * 33 + n];
      inv[r] = 4096.0f / (float)lu;
    }
    unsigned short* obase =
        attn16 + ((size_t)(b * 512 + qb + ws4 * 16 + qd * 4)) * 512 + (h << 6);
#pragma unroll
    for (int r = 0; r < 4; ++r)
#pragma unroll
      for (int dt = 0; dt < 4; ++dt) {
        float v = (acc[dt][r] + accbuf[ws4 * 1088 + (qd * 4 + r) * 68 + dt * 16 + ln]) * inv[r];
        obase[(size_t)r * 512 + dt * 16 + ln] = f2bf(v);
      }
  }
}

// ---------------------------------------------------------------------------
extern "C" void kernel_launch(void* const* d_in, const int* in_sizes, int n_in,
                              void* d_out, int out_size, void* d_ws, size_t ws_size,
                              hipStream_t stream) {
  const float* x = (const float*)d_in[0];
  const int* rel = (const int*)d_in[1];
  const unsigned char* mask = (const unsigned char*)d_in[2];
  const float* qpe = (const float*)d_in[3];
  const float* kpe = (const float*)d_in[4];
  const float* vpe = (const float*)d_in[5];
  const float* Wq = (const float*)d_in[6];
  const float* Wk = (const float*)d_in[7];
  const float* Wv = (const float*)d_in[8];
  const float* Wo = (const float*)d_in[9];
  float* out = (float*)d_out;

  unsigned short* u = (unsigned short*)d_ws;
  unsigned short* x16    = u;                    // 2,097,152
  unsigned short* w16q   = x16 + 2097152;        //   262,144
  unsigned short* w16k   = w16q + 262144;        //   524,288
  unsigned short* w16v   = w16k + 524288;        //   524,288
  unsigned short* w16o   = w16v + 524288;        //   262,144
  unsigned short* wqp16  = w16o + 262144;        //   131,072  (256x512)
  unsigned short* wkp16  = wqp16 + 131072;       //   262,144  (512x512)
  unsigned short* q16h   = wkp16 + 262144;       // 2,097,152
  unsigned short* qpw16  = q16h + 2097152;       // 1,048,576  [b,h,s,32]
  unsigned short* kb16   = qpw16 + 1048576;      // 4,194,304
  unsigned short* kpw16  = kb16 + 4194304;       // 2,097,152  [b,h,k2,32]
  unsigned short* vT16   = kpw16 + 2097152;      // 4,194,304
  unsigned short* attn16 = vT16 + 4194304;       // 2,097,152
  unsigned char* pk8 = (unsigned char*)(attn16 + 2097152);  // 4 MB  -> ~44 MB total

  pack_k<<<1024, 256, 0, stream>>>(rel, mask, pk8);
  cvt5_k<<<3584, 256, 0, stream>>>(x, Wq, Wk, Wv, Wo, x16, w16q, w16k, w16v, w16o);
  wemb_k<<<96, 256, 0, stream>>>(qpe, kpe, Wq, Wk, wqp16, wkp16);
  gemm16_k<1><<<dim3(12, 64), 256, 0, stream>>>(x16, w16q, wqp16, q16h, qpw16,
                                                4096, 768, 512, 512);
  gemm16_k<2><<<dim3(24, 64), 256, 0, stream>>>(x16, w16k, wkp16, kb16, kpw16,
                                                4096, 1536, 512, 1024);
  gemm16_k<3><<<dim3(16, 64), 256, 0, stream>>>(x16, w16v, nullptr, vT16, nullptr,
                                                4096, 1024, 512, 1024);
  attn8_k<<<512, 512, 0, stream>>>(q16h, kb16, vT16, qpw16, kpw16, pk8, vpe, attn16);
  gemm16_k<0><<<dim3(8, 64), 256, 0, stream>>>(attn16, w16o, nullptr, out, nullptr,
                                               4096, 512, 512, 512);
}